// Round 1
// baseline (623.512 us; speedup 1.0000x reference)
//
#include <hip/hip_runtime.h>
#include <hip/hip_bf16.h>

// Biattention: x:[8,2048,1024] f32, mask:[8,2048] i32
// out = concat([x, c, x+c, x-c, x*c], -1) where c = softmax(mask(x x^T)) x
//
// Pipeline:
//  K1 prep:    x -> x_hi(bf16), x_lo(bf16), x_hiT(bf16 transposed)
//  K2 scores:  S = x x^T via split-bf16 3-pass MFMA GEMM (K folded to 3072)
//  K3 softmax: P = softmax_masked(S) in bf16 (wave per row)
//  K4 context: C = P @ x_hi (NT via x_hiT), fused 5-chunk epilogue

typedef __attribute__((ext_vector_type(8))) __bf16 bf16x8;
typedef __attribute__((ext_vector_type(4))) float f32x4;

#define SEQ 2048
#define DIM 1024
#define NBATCH 8

__device__ __forceinline__ unsigned short f2bf(float f) {
  union { __hip_bfloat16 h; unsigned short u; } cv;
  cv.h = __float2bfloat16(f);
  return cv.u;
}
__device__ __forceinline__ float bf2f(unsigned short u) {
  union { __hip_bfloat16 h; unsigned short u; } cv;
  cv.u = u;
  return __bfloat162float(cv.h);
}

__device__ __forceinline__ void load16(const void* g, void* l) {
  __builtin_amdgcn_global_load_lds(
      (const __attribute__((address_space(1))) unsigned int*)g,
      (__attribute__((address_space(3))) unsigned int*)l, 16, 0, 0);
}

// ---------------- K1: convert + transpose ----------------
// grid (S/32, D/32, B), block 256
__global__ __launch_bounds__(256) void k_prep(
    const float* __restrict__ x, unsigned short* __restrict__ xh,
    unsigned short* __restrict__ xl, unsigned short* __restrict__ xT) {
  __shared__ unsigned short tile[32][33];
  int b = blockIdx.z;
  int s0 = blockIdx.x * 32;
  int d0 = blockIdx.y * 32;
  int t = threadIdx.x;
  int r = t >> 3;          // 0..31
  int c4 = (t & 7) * 4;    // 0..28

  long src = (long)(b * SEQ + s0 + r) * DIM + d0 + c4;
  float4 v = *(const float4*)(x + src);
  float vv[4] = {v.x, v.y, v.z, v.w};
  unsigned short hu[4], lu[4];
#pragma unroll
  for (int j = 0; j < 4; ++j) {
    hu[j] = f2bf(vv[j]);
    float hf = bf2f(hu[j]);
    lu[j] = f2bf(vv[j] - hf);
    tile[r][c4 + j] = hu[j];
  }
  *(ushort4*)(xh + src) = make_ushort4(hu[0], hu[1], hu[2], hu[3]);
  *(ushort4*)(xl + src) = make_ushort4(lu[0], lu[1], lu[2], lu[3]);
  __syncthreads();
  // transposed write: xT[b][d0+r][s0+c4..]
  unsigned short tv[4];
#pragma unroll
  for (int j = 0; j < 4; ++j) tv[j] = tile[c4 + j][r];
  long dst = (long)(b * DIM + d0 + r) * SEQ + s0 + c4;
  *(ushort4*)(xT + dst) = make_ushort4(tv[0], tv[1], tv[2], tv[3]);
}

// ---------------- K2: scores GEMM (NT, split-bf16 3-pass) ----------------
// 128x128 tile, BK=32, 4 waves each owning a 64x64 quadrant (4x4 MFMA frags)
// grid (16 ncol, 16 mrow, 8 batch), block 256
#define BK 32

__global__ __launch_bounds__(256) void k_scores(
    const unsigned short* __restrict__ xh, const unsigned short* __restrict__ xl,
    float* __restrict__ S) {
  __shared__ unsigned short As[128 * BK];
  __shared__ unsigned short Bs[128 * BK];
  int b = blockIdx.z;
  int m0 = blockIdx.y * 128;
  int n0 = blockIdx.x * 128;
  const unsigned short* xh_b = xh + (long)b * SEQ * DIM;
  const unsigned short* xl_b = xl + (long)b * SEQ * DIM;
  float* S_b = S + (long)b * SEQ * SEQ;

  int tid = threadIdx.x;
  int w = tid >> 6, lane = tid & 63;
  int wr = w >> 1, wc = w & 1;
  int l15 = lane & 15, lhi = lane >> 4;

  f32x4 acc[4][4];
#pragma unroll
  for (int m = 0; m < 4; ++m)
#pragma unroll
    for (int n = 0; n < 4; ++n)
#pragma unroll
      for (int j = 0; j < 4; ++j) acc[m][n][j] = 0.0f;

  for (int kt = 0; kt < 3072 / BK; ++kt) {
    int k0 = kt * BK;
    int p = k0 >> 10;       // 0: hi*hi  1: hi*lo  2: lo*hi
    int kk = k0 & 1023;
    const unsigned short* Asrc = (p == 2) ? xl_b : xh_b;
    const unsigned short* Bsrc = (p == 1) ? xl_b : xh_b;
#pragma unroll
    for (int i = 0; i < 2; ++i) {
      int cbase = i * 256 + w * 64;   // wave-uniform chunk base
      int c = cbase + lane;           // 16B chunk index 0..511
      int row = c >> 2;
      int kc = (c & 3) * 8;
      load16(Asrc + (long)(m0 + row) * DIM + kk + kc, &As[cbase * 8]);
      load16(Bsrc + (long)(n0 + row) * DIM + kk + kc, &Bs[cbase * 8]);
    }
    __syncthreads();
    bf16x8 af[4], bg[4];
#pragma unroll
    for (int m = 0; m < 4; ++m)
      af[m] = *(const bf16x8*)&As[(wr * 64 + m * 16 + l15) * BK + lhi * 8];
#pragma unroll
    for (int n = 0; n < 4; ++n)
      bg[n] = *(const bf16x8*)&Bs[(wc * 64 + n * 16 + l15) * BK + lhi * 8];
#pragma unroll
    for (int m = 0; m < 4; ++m)
#pragma unroll
      for (int n = 0; n < 4; ++n)
        acc[m][n] = __builtin_amdgcn_mfma_f32_16x16x32_bf16(af[m], bg[n], acc[m][n], 0, 0, 0);
    __syncthreads();
  }
#pragma unroll
  for (int m = 0; m < 4; ++m)
#pragma unroll
    for (int n = 0; n < 4; ++n)
#pragma unroll
      for (int j = 0; j < 4; ++j) {
        int r = m0 + wr * 64 + m * 16 + lhi * 4 + j;
        int c = n0 + wc * 64 + n * 16 + l15;
        S_b[(long)r * SEQ + c] = acc[m][n][j];
      }
}

// ---------------- K3: masked softmax, wave per row ----------------
// grid 4096, block 256 (4 waves = 4 rows)
__global__ __launch_bounds__(256) void k_softmax(
    const float* __restrict__ S, const int* __restrict__ mask,
    unsigned short* __restrict__ P) {
  int w = threadIdx.x >> 6, lane = threadIdx.x & 63;
  long row = (long)blockIdx.x * 4 + w;  // 0..16383
  int b = (int)(row >> 11);
  const float* Sp = S + row * SEQ;
  const int* mp = mask + b * SEQ;
  unsigned short* Pp = P + row * SEQ;

  float sv[32];
  float mx = -__builtin_inff();
#pragma unroll
  for (int ci = 0; ci < 8; ++ci) {
    int col = ci * 256 + lane * 4;
    float4 v = *(const float4*)(Sp + col);
    int4 mk = *(const int4*)(mp + col);
    sv[ci * 4 + 0] = mk.x ? v.x : -__builtin_inff();
    sv[ci * 4 + 1] = mk.y ? v.y : -__builtin_inff();
    sv[ci * 4 + 2] = mk.z ? v.z : -__builtin_inff();
    sv[ci * 4 + 3] = mk.w ? v.w : -__builtin_inff();
    mx = fmaxf(mx, fmaxf(fmaxf(sv[ci * 4 + 0], sv[ci * 4 + 1]),
                         fmaxf(sv[ci * 4 + 2], sv[ci * 4 + 3])));
  }
#pragma unroll
  for (int off = 32; off; off >>= 1) mx = fmaxf(mx, __shfl_xor(mx, off));
  float pv[32];
  float sum = 0.0f;
#pragma unroll
  for (int i = 0; i < 32; ++i) {
    pv[i] = expf(sv[i] - mx);
    sum += pv[i];
  }
#pragma unroll
  for (int off = 32; off; off >>= 1) sum += __shfl_xor(sum, off);
  float inv = 1.0f / sum;
#pragma unroll
  for (int ci = 0; ci < 8; ++ci) {
    int col = ci * 256 + lane * 4;
    *(ushort4*)(Pp + col) = make_ushort4(
        f2bf(pv[ci * 4 + 0] * inv), f2bf(pv[ci * 4 + 1] * inv),
        f2bf(pv[ci * 4 + 2] * inv), f2bf(pv[ci * 4 + 3] * inv));
  }
}

// ---------------- K4: context GEMM (NT) + fused epilogue ----------------
// A = P [q][key] lda=2048, B = xT [d][key] ldb=2048, C[q][d]
// grid (8 ncol, 16 mrow, 8 batch), block 256
__global__ __launch_bounds__(256) void k_context(
    const unsigned short* __restrict__ P, const unsigned short* __restrict__ xT,
    const float* __restrict__ x, float* __restrict__ out) {
  __shared__ unsigned short As[128 * BK];
  __shared__ unsigned short Bs[128 * BK];
  int b = blockIdx.z;
  int m0 = blockIdx.y * 128;  // query rows
  int n0 = blockIdx.x * 128;  // d cols
  const unsigned short* A_b = P + (long)b * SEQ * SEQ;
  const unsigned short* B_b = xT + (long)b * DIM * SEQ;

  int tid = threadIdx.x;
  int w = tid >> 6, lane = tid & 63;
  int wr = w >> 1, wc = w & 1;
  int l15 = lane & 15, lhi = lane >> 4;

  f32x4 acc[4][4];
#pragma unroll
  for (int m = 0; m < 4; ++m)
#pragma unroll
    for (int n = 0; n < 4; ++n)
#pragma unroll
      for (int j = 0; j < 4; ++j) acc[m][n][j] = 0.0f;

  for (int kt = 0; kt < SEQ / BK; ++kt) {
    int kk = kt * BK;
#pragma unroll
    for (int i = 0; i < 2; ++i) {
      int cbase = i * 256 + w * 64;
      int c = cbase + lane;
      int row = c >> 2;
      int kc = (c & 3) * 8;
      load16(A_b + (long)(m0 + row) * SEQ + kk + kc, &As[cbase * 8]);
      load16(B_b + (long)(n0 + row) * SEQ + kk + kc, &Bs[cbase * 8]);
    }
    __syncthreads();
    bf16x8 af[4], bg[4];
#pragma unroll
    for (int m = 0; m < 4; ++m)
      af[m] = *(const bf16x8*)&As[(wr * 64 + m * 16 + l15) * BK + lhi * 8];
#pragma unroll
    for (int n = 0; n < 4; ++n)
      bg[n] = *(const bf16x8*)&Bs[(wc * 64 + n * 16 + l15) * BK + lhi * 8];
#pragma unroll
    for (int m = 0; m < 4; ++m)
#pragma unroll
      for (int n = 0; n < 4; ++n)
        acc[m][n] = __builtin_amdgcn_mfma_f32_16x16x32_bf16(af[m], bg[n], acc[m][n], 0, 0, 0);
    __syncthreads();
  }

  const float* x_b = x + (long)b * SEQ * DIM;
  float* out_b = out + (long)b * SEQ * (5 * DIM);
#pragma unroll
  for (int m = 0; m < 4; ++m)
#pragma unroll
    for (int n = 0; n < 4; ++n)
#pragma unroll
      for (int j = 0; j < 4; ++j) {
        int q = m0 + wr * 64 + m * 16 + lhi * 4 + j;
        int d = n0 + wc * 64 + n * 16 + l15;
        float c = acc[m][n][j];
        float xv = x_b[(long)q * DIM + d];
        long base = (long)q * (5 * DIM) + d;
        out_b[base] = xv;
        out_b[base + DIM] = c;
        out_b[base + 2 * DIM] = xv + c;
        out_b[base + 3 * DIM] = xv - c;
        out_b[base + 4 * DIM] = xv * c;
      }
}

extern "C" void kernel_launch(void* const* d_in, const int* in_sizes, int n_in,
                              void* d_out, int out_size, void* d_ws, size_t ws_size,
                              hipStream_t stream) {
  const float* x = (const float*)d_in[0];
  const int* mask = (const int*)d_in[1];
  float* out = (float*)d_out;
  char* ws = (char*)d_ws;

  const size_t HB = (size_t)NBATCH * SEQ * DIM * 2;  // 33,554,432 B (bf16 x)
  unsigned short* xh = (unsigned short*)ws;
  unsigned short* xl = (unsigned short*)(ws + HB);
  unsigned short* xT = (unsigned short*)(ws + 2 * HB);
  unsigned short* P = (unsigned short*)(ws + 3 * HB);               // 67,108,864 B
  const size_t PB = (size_t)NBATCH * SEQ * SEQ * 2;
  const size_t SB = (size_t)NBATCH * SEQ * SEQ * 4;                 // 134,217,728 B
  float* S;
  if (ws_size >= 3 * HB + PB + SB) {
    S = (float*)(ws + 3 * HB + PB);
  } else {
    // S is dead before K4 writes out: alias into d_out (stream-ordered)
    S = (float*)d_out;
  }

  k_prep<<<dim3(SEQ / 32, DIM / 32, NBATCH), 256, 0, stream>>>(x, xh, xl, xT);
  k_scores<<<dim3(SEQ / 128, SEQ / 128, NBATCH), 256, 0, stream>>>(xh, xl, S);
  k_softmax<<<NBATCH * SEQ / 4, 256, 0, stream>>>(S, mask, P);
  k_context<<<dim3(DIM / 128, SEQ / 128, NBATCH), 256, 0, stream>>>(P, xT, x, out);
}

// Round 2
// 546.917 us; speedup vs baseline: 1.1400x; 1.1400x over previous
//
#include <hip/hip_runtime.h>
#include <hip/hip_bf16.h>

// Biattention: x:[8,2048,1024] f32, mask:[8,2048] i32
// out = concat([x, c, x+c, x-c, x*c], -1) where c = softmax(mask(x x^T)) x
//
// Pipeline:
//  K1 prep:    x -> x_hi(bf16), x_lo(bf16), x_hiT(bf16 transposed)
//  K2 scores:  S = x x^T via split-bf16 3-pass MFMA GEMM (K folded to 3072)
//              SYMMETRIC: only triangular blocks computed, transposed f32x4 store
//  K3 softmax: P = softmax_masked(S) in bf16 (wave per row)
//  K4 context: C = P @ x_hi (NT via x_hiT), fused 5-chunk epilogue
//
// LDS bank-conflict fix (T2 + rule #21): global_load_lds writes linearly, so
// the 16B chunk each lane FETCHES is permuted (kc4 ^= (row>>1)&3) and the
// fragment read applies the same XOR -> bank_base = 16*(row&1)+4*(lhi^swz)
// spans all 8 groups over 8 rows -> 2-way residual (free).

typedef __attribute__((ext_vector_type(8))) __bf16 bf16x8;
typedef __attribute__((ext_vector_type(4))) float f32x4;

#define SEQ 2048
#define DIM 1024
#define NBATCH 8
#define BK 32

__device__ __forceinline__ unsigned short f2bf(float f) {
  union { __hip_bfloat16 h; unsigned short u; } cv;
  cv.h = __float2bfloat16(f);
  return cv.u;
}
__device__ __forceinline__ float bf2f(unsigned short u) {
  union { __hip_bfloat16 h; unsigned short u; } cv;
  cv.u = u;
  return __bfloat162float(cv.h);
}

__device__ __forceinline__ void load16(const void* g, void* l) {
  __builtin_amdgcn_global_load_lds(
      (const __attribute__((address_space(1))) unsigned int*)g,
      (__attribute__((address_space(3))) unsigned int*)l, 16, 0, 0);
}

// ---------------- K1: convert + transpose ----------------
__global__ __launch_bounds__(256) void k_prep(
    const float* __restrict__ x, unsigned short* __restrict__ xh,
    unsigned short* __restrict__ xl, unsigned short* __restrict__ xT) {
  __shared__ unsigned short tile[32][33];
  int b = blockIdx.z;
  int s0 = blockIdx.x * 32;
  int d0 = blockIdx.y * 32;
  int t = threadIdx.x;
  int r = t >> 3;
  int c4 = (t & 7) * 4;

  long src = (long)(b * SEQ + s0 + r) * DIM + d0 + c4;
  float4 v = *(const float4*)(x + src);
  float vv[4] = {v.x, v.y, v.z, v.w};
  unsigned short hu[4], lu[4];
#pragma unroll
  for (int j = 0; j < 4; ++j) {
    hu[j] = f2bf(vv[j]);
    float hf = bf2f(hu[j]);
    lu[j] = f2bf(vv[j] - hf);
    tile[r][c4 + j] = hu[j];
  }
  *(ushort4*)(xh + src) = make_ushort4(hu[0], hu[1], hu[2], hu[3]);
  *(ushort4*)(xl + src) = make_ushort4(lu[0], lu[1], lu[2], lu[3]);
  __syncthreads();
  unsigned short tv[4];
#pragma unroll
  for (int j = 0; j < 4; ++j) tv[j] = tile[c4 + j][r];
  long dst = (long)(b * DIM + d0 + r) * SEQ + s0 + c4;
  *(ushort4*)(xT + dst) = make_ushort4(tv[0], tv[1], tv[2], tv[3]);
}

// ---------------- K2: scores GEMM (NT, split-bf16, symmetric) ----------------
// grid (136 tri-blocks, 1, 8 batch), block 256
__global__ __launch_bounds__(256) void k_scores(
    const unsigned short* __restrict__ xh, const unsigned short* __restrict__ xl,
    float* __restrict__ S) {
  __shared__ unsigned short As[128 * BK];
  __shared__ unsigned short Bs[128 * BK];
  int b = blockIdx.z;
  // triangular decode: blockIdx.x -> (bm, bn) with bm <= bn
  int t = blockIdx.x, bm = 0, rem = 16;
  while (t >= rem) { t -= rem; ++bm; --rem; }
  int bn = bm + t;
  int m0 = bm * 128;
  int n0 = bn * 128;
  const unsigned short* xh_b = xh + (long)b * SEQ * DIM;
  const unsigned short* xl_b = xl + (long)b * SEQ * DIM;
  float* S_b = S + (long)b * SEQ * SEQ;

  int tid = threadIdx.x;
  int w = tid >> 6, lane = tid & 63;
  int wr = w >> 1, wc = w & 1;
  int l15 = lane & 15, lhi = lane >> 4;

  f32x4 acc[4][4];
#pragma unroll
  for (int m = 0; m < 4; ++m)
#pragma unroll
    for (int n = 0; n < 4; ++n)
#pragma unroll
      for (int j = 0; j < 4; ++j) acc[m][n][j] = 0.0f;

  for (int kt = 0; kt < 3072 / BK; ++kt) {
    int k0 = kt * BK;
    int p = k0 >> 10;       // 0: hi*hi  1: hi*lo  2: lo*hi
    int kk = k0 & 1023;
    const unsigned short* Asrc = (p == 2) ? xl_b : xh_b;
    const unsigned short* Bsrc = (p == 1) ? xl_b : xh_b;
#pragma unroll
    for (int i = 0; i < 2; ++i) {
      int cbase = i * 256 + w * 64;   // wave-uniform chunk base
      int c = cbase + lane;           // 16B chunk index 0..511
      int row = c >> 2;
      int kc4 = (c & 3) ^ ((row >> 1) & 3);   // pre-swizzled global source
      load16(Asrc + (long)(m0 + row) * DIM + kk + kc4 * 8, &As[cbase * 8]);
      load16(Bsrc + (long)(n0 + row) * DIM + kk + kc4 * 8, &Bs[cbase * 8]);
    }
    __syncthreads();
    bf16x8 af[4], bg[4];
#pragma unroll
    for (int m = 0; m < 4; ++m) {
      int R = wr * 64 + m * 16 + l15;
      af[m] = *(const bf16x8*)&As[R * BK + ((lhi ^ ((R >> 1) & 3)) * 8)];
    }
#pragma unroll
    for (int n = 0; n < 4; ++n) {
      int R = wc * 64 + n * 16 + l15;
      bg[n] = *(const bf16x8*)&Bs[R * BK + ((lhi ^ ((R >> 1) & 3)) * 8)];
    }
#pragma unroll
    for (int m = 0; m < 4; ++m)
#pragma unroll
      for (int n = 0; n < 4; ++n)
        acc[m][n] = __builtin_amdgcn_mfma_f32_16x16x32_bf16(af[m], bg[n], acc[m][n], 0, 0, 0);
    __syncthreads();
  }
  // normal-orientation write: S[r][c]
#pragma unroll
  for (int m = 0; m < 4; ++m)
#pragma unroll
    for (int n = 0; n < 4; ++n)
#pragma unroll
      for (int j = 0; j < 4; ++j) {
        int r = m0 + wr * 64 + m * 16 + lhi * 4 + j;
        int c = n0 + wc * 64 + n * 16 + l15;
        S_b[(long)r * SEQ + c] = acc[m][n][j];
      }
  // transposed write for off-diagonal blocks: S[c][r0..r0+3] = acc (float4)
  if (bm != bn) {
#pragma unroll
    for (int m = 0; m < 4; ++m)
#pragma unroll
      for (int n = 0; n < 4; ++n) {
        int r0 = m0 + wr * 64 + m * 16 + lhi * 4;
        int c = n0 + wc * 64 + n * 16 + l15;
        *(f32x4*)&S_b[(long)c * SEQ + r0] = acc[m][n];
      }
  }
}

// ---------------- K3: masked softmax, wave per row ----------------
__global__ __launch_bounds__(256) void k_softmax(
    const float* __restrict__ S, const int* __restrict__ mask,
    unsigned short* __restrict__ P) {
  int w = threadIdx.x >> 6, lane = threadIdx.x & 63;
  long row = (long)blockIdx.x * 4 + w;
  int b = (int)(row >> 11);
  const float* Sp = S + row * SEQ;
  const int* mp = mask + b * SEQ;
  unsigned short* Pp = P + row * SEQ;

  float sv[32];
  float mx = -__builtin_inff();
#pragma unroll
  for (int ci = 0; ci < 8; ++ci) {
    int col = ci * 256 + lane * 4;
    float4 v = *(const float4*)(Sp + col);
    int4 mk = *(const int4*)(mp + col);
    sv[ci * 4 + 0] = mk.x ? v.x : -__builtin_inff();
    sv[ci * 4 + 1] = mk.y ? v.y : -__builtin_inff();
    sv[ci * 4 + 2] = mk.z ? v.z : -__builtin_inff();
    sv[ci * 4 + 3] = mk.w ? v.w : -__builtin_inff();
    mx = fmaxf(mx, fmaxf(fmaxf(sv[ci * 4 + 0], sv[ci * 4 + 1]),
                         fmaxf(sv[ci * 4 + 2], sv[ci * 4 + 3])));
  }
#pragma unroll
  for (int off = 32; off; off >>= 1) mx = fmaxf(mx, __shfl_xor(mx, off));
  float pv[32];
  float sum = 0.0f;
#pragma unroll
  for (int i = 0; i < 32; ++i) {
    pv[i] = expf(sv[i] - mx);
    sum += pv[i];
  }
#pragma unroll
  for (int off = 32; off; off >>= 1) sum += __shfl_xor(sum, off);
  float inv = 1.0f / sum;
#pragma unroll
  for (int ci = 0; ci < 8; ++ci) {
    int col = ci * 256 + lane * 4;
    *(ushort4*)(Pp + col) = make_ushort4(
        f2bf(pv[ci * 4 + 0] * inv), f2bf(pv[ci * 4 + 1] * inv),
        f2bf(pv[ci * 4 + 2] * inv), f2bf(pv[ci * 4 + 3] * inv));
  }
}

// ---------------- K4: context GEMM (NT) + fused epilogue ----------------
__global__ __launch_bounds__(256) void k_context(
    const unsigned short* __restrict__ P, const unsigned short* __restrict__ xT,
    const float* __restrict__ x, float* __restrict__ out) {
  __shared__ unsigned short As[128 * BK];
  __shared__ unsigned short Bs[128 * BK];
  int b = blockIdx.z;
  int m0 = blockIdx.y * 128;  // query rows
  int n0 = blockIdx.x * 128;  // d cols
  const unsigned short* A_b = P + (long)b * SEQ * SEQ;
  const unsigned short* B_b = xT + (long)b * DIM * SEQ;

  int tid = threadIdx.x;
  int w = tid >> 6, lane = tid & 63;
  int wr = w >> 1, wc = w & 1;
  int l15 = lane & 15, lhi = lane >> 4;

  f32x4 acc[4][4];
#pragma unroll
  for (int m = 0; m < 4; ++m)
#pragma unroll
    for (int n = 0; n < 4; ++n)
#pragma unroll
      for (int j = 0; j < 4; ++j) acc[m][n][j] = 0.0f;

  for (int kt = 0; kt < SEQ / BK; ++kt) {
    int kk = kt * BK;
#pragma unroll
    for (int i = 0; i < 2; ++i) {
      int cbase = i * 256 + w * 64;
      int c = cbase + lane;
      int row = c >> 2;
      int kc4 = (c & 3) ^ ((row >> 1) & 3);
      load16(A_b + (long)(m0 + row) * SEQ + kk + kc4 * 8, &As[cbase * 8]);
      load16(B_b + (long)(n0 + row) * SEQ + kk + kc4 * 8, &Bs[cbase * 8]);
    }
    __syncthreads();
    bf16x8 af[4], bg[4];
#pragma unroll
    for (int m = 0; m < 4; ++m) {
      int R = wr * 64 + m * 16 + l15;
      af[m] = *(const bf16x8*)&As[R * BK + ((lhi ^ ((R >> 1) & 3)) * 8)];
    }
#pragma unroll
    for (int n = 0; n < 4; ++n) {
      int R = wc * 64 + n * 16 + l15;
      bg[n] = *(const bf16x8*)&Bs[R * BK + ((lhi ^ ((R >> 1) & 3)) * 8)];
    }
#pragma unroll
    for (int m = 0; m < 4; ++m)
#pragma unroll
      for (int n = 0; n < 4; ++n)
        acc[m][n] = __builtin_amdgcn_mfma_f32_16x16x32_bf16(af[m], bg[n], acc[m][n], 0, 0, 0);
    __syncthreads();
  }

  const float* x_b = x + (long)b * SEQ * DIM;
  float* out_b = out + (long)b * SEQ * (5 * DIM);
#pragma unroll
  for (int m = 0; m < 4; ++m)
#pragma unroll
    for (int n = 0; n < 4; ++n)
#pragma unroll
      for (int j = 0; j < 4; ++j) {
        int q = m0 + wr * 64 + m * 16 + lhi * 4 + j;
        int d = n0 + wc * 64 + n * 16 + l15;
        float c = acc[m][n][j];
        float xv = x_b[(long)q * DIM + d];
        long base = (long)q * (5 * DIM) + d;
        out_b[base] = xv;
        out_b[base + DIM] = c;
        out_b[base + 2 * DIM] = xv + c;
        out_b[base + 3 * DIM] = xv - c;
        out_b[base + 4 * DIM] = xv * c;
      }
}

extern "C" void kernel_launch(void* const* d_in, const int* in_sizes, int n_in,
                              void* d_out, int out_size, void* d_ws, size_t ws_size,
                              hipStream_t stream) {
  const float* x = (const float*)d_in[0];
  const int* mask = (const int*)d_in[1];
  float* out = (float*)d_out;
  char* ws = (char*)d_ws;

  const size_t HB = (size_t)NBATCH * SEQ * DIM * 2;
  unsigned short* xh = (unsigned short*)ws;
  unsigned short* xl = (unsigned short*)(ws + HB);
  unsigned short* xT = (unsigned short*)(ws + 2 * HB);
  unsigned short* P = (unsigned short*)(ws + 3 * HB);
  const size_t PB = (size_t)NBATCH * SEQ * SEQ * 2;
  const size_t SB = (size_t)NBATCH * SEQ * SEQ * 4;
  float* S;
  if (ws_size >= 3 * HB + PB + SB) {
    S = (float*)(ws + 3 * HB + PB);
  } else {
    S = (float*)d_out;  // S dead before K4 writes out
  }

  k_prep<<<dim3(SEQ / 32, DIM / 32, NBATCH), 256, 0, stream>>>(x, xh, xl, xT);
  k_scores<<<dim3(136, 1, NBATCH), 256, 0, stream>>>(xh, xl, S);
  k_softmax<<<NBATCH * SEQ / 4, 256, 0, stream>>>(S, mask, P);
  k_context<<<dim3(DIM / 128, SEQ / 128, NBATCH), 256, 0, stream>>>(P, xT, x, out);
}

// Round 3
// 509.093 us; speedup vs baseline: 1.2247x; 1.0743x over previous
//
#include <hip/hip_runtime.h>
#include <hip/hip_bf16.h>

// Biattention: x:[8,2048,1024] f32, mask:[8,2048] i32
// out = concat([x, c, x+c, x-c, x*c], -1) where c = softmax(mask(x x^T)) x
//
// Pipeline:
//  K1 prep:    x -> x_hi(bf16), x_lo(bf16), x_hiT(bf16 transposed)
//  K2 scores:  S = x x^T via split-bf16 3-pass MFMA GEMM, symmetric (tri blocks)
//              + batch-per-XCD block swizzle (T1)
//  K3 softmax: P = softmax_masked(S) in bf16 (wave per row)
//  K4 context: C = P @ x_hi (NT via x_hiT), fused 5-chunk epilogue
//              + batch-per-XCD swizzle (T1) + double-buffered prefetch (T3-min)
//
// LDS bank-conflict fix (T2 + rule #21): global_load_lds writes linearly, so
// the 16B chunk each lane FETCHES is permuted (kc4 ^= (row>>1)&3) and the
// fragment read applies the same XOR (verified R2: SQ_LDS_BANK_CONFLICT = 0).

typedef __attribute__((ext_vector_type(8))) __bf16 bf16x8;
typedef __attribute__((ext_vector_type(4))) float f32x4;

#define SEQ 2048
#define DIM 1024
#define NBATCH 8
#define BK 32

__device__ __forceinline__ unsigned short f2bf(float f) {
  union { __hip_bfloat16 h; unsigned short u; } cv;
  cv.h = __float2bfloat16(f);
  return cv.u;
}
__device__ __forceinline__ float bf2f(unsigned short u) {
  union { __hip_bfloat16 h; unsigned short u; } cv;
  cv.u = u;
  return __bfloat162float(cv.h);
}

__device__ __forceinline__ void load16(const void* g, void* l) {
  __builtin_amdgcn_global_load_lds(
      (const __attribute__((address_space(1))) unsigned int*)g,
      (__attribute__((address_space(3))) unsigned int*)l, 16, 0, 0);
}

// ---------------- K1: convert + transpose ----------------
__global__ __launch_bounds__(256) void k_prep(
    const float* __restrict__ x, unsigned short* __restrict__ xh,
    unsigned short* __restrict__ xl, unsigned short* __restrict__ xT) {
  __shared__ unsigned short tile[32][33];
  int b = blockIdx.z;
  int s0 = blockIdx.x * 32;
  int d0 = blockIdx.y * 32;
  int t = threadIdx.x;
  int r = t >> 3;
  int c4 = (t & 7) * 4;

  long src = (long)(b * SEQ + s0 + r) * DIM + d0 + c4;
  float4 v = *(const float4*)(x + src);
  float vv[4] = {v.x, v.y, v.z, v.w};
  unsigned short hu[4], lu[4];
#pragma unroll
  for (int j = 0; j < 4; ++j) {
    hu[j] = f2bf(vv[j]);
    float hf = bf2f(hu[j]);
    lu[j] = f2bf(vv[j] - hf);
    tile[r][c4 + j] = hu[j];
  }
  *(ushort4*)(xh + src) = make_ushort4(hu[0], hu[1], hu[2], hu[3]);
  *(ushort4*)(xl + src) = make_ushort4(lu[0], lu[1], lu[2], lu[3]);
  __syncthreads();
  unsigned short tv[4];
#pragma unroll
  for (int j = 0; j < 4; ++j) tv[j] = tile[c4 + j][r];
  long dst = (long)(b * DIM + d0 + r) * SEQ + s0 + c4;
  *(ushort4*)(xT + dst) = make_ushort4(tv[0], tv[1], tv[2], tv[3]);
}

// ---------------- K2: scores GEMM (NT, split-bf16, symmetric) ----------------
// grid (136, 1, 8); batch-per-XCD swizzle: b = p%8, tri-index = p/8
__global__ __launch_bounds__(256) void k_scores(
    const unsigned short* __restrict__ xh, const unsigned short* __restrict__ xl,
    float* __restrict__ S) {
  __shared__ unsigned short As[128 * BK];
  __shared__ unsigned short Bs[128 * BK];
  int p = blockIdx.x + 136 * blockIdx.z;   // linear dispatch id, 0..1087
  int b = p & 7;                            // XCD-aligned: one batch per XCD
  int t = p >> 3;                           // tri-index 0..135
  int bm = 0, rem = 16;
  while (t >= rem) { t -= rem; ++bm; --rem; }
  int bn = bm + t;
  int m0 = bm * 128;
  int n0 = bn * 128;
  const unsigned short* xh_b = xh + (long)b * SEQ * DIM;
  const unsigned short* xl_b = xl + (long)b * SEQ * DIM;
  float* S_b = S + (long)b * SEQ * SEQ;

  int tid = threadIdx.x;
  int w = tid >> 6, lane = tid & 63;
  int wr = w >> 1, wc = w & 1;
  int l15 = lane & 15, lhi = lane >> 4;

  f32x4 acc[4][4];
#pragma unroll
  for (int m = 0; m < 4; ++m)
#pragma unroll
    for (int n = 0; n < 4; ++n)
#pragma unroll
      for (int j = 0; j < 4; ++j) acc[m][n][j] = 0.0f;

  for (int kt = 0; kt < 3072 / BK; ++kt) {
    int k0 = kt * BK;
    int pp = k0 >> 10;      // 0: hi*hi  1: hi*lo  2: lo*hi
    int kk = k0 & 1023;
    const unsigned short* Asrc = (pp == 2) ? xl_b : xh_b;
    const unsigned short* Bsrc = (pp == 1) ? xl_b : xh_b;
#pragma unroll
    for (int i = 0; i < 2; ++i) {
      int cbase = i * 256 + w * 64;
      int c = cbase + lane;
      int row = c >> 2;
      int kc4 = (c & 3) ^ ((row >> 1) & 3);
      load16(Asrc + (long)(m0 + row) * DIM + kk + kc4 * 8, &As[cbase * 8]);
      load16(Bsrc + (long)(n0 + row) * DIM + kk + kc4 * 8, &Bs[cbase * 8]);
    }
    __syncthreads();
    bf16x8 af[4], bg[4];
#pragma unroll
    for (int m = 0; m < 4; ++m) {
      int R = wr * 64 + m * 16 + l15;
      af[m] = *(const bf16x8*)&As[R * BK + ((lhi ^ ((R >> 1) & 3)) * 8)];
    }
#pragma unroll
    for (int n = 0; n < 4; ++n) {
      int R = wc * 64 + n * 16 + l15;
      bg[n] = *(const bf16x8*)&Bs[R * BK + ((lhi ^ ((R >> 1) & 3)) * 8)];
    }
#pragma unroll
    for (int m = 0; m < 4; ++m)
#pragma unroll
      for (int n = 0; n < 4; ++n)
        acc[m][n] = __builtin_amdgcn_mfma_f32_16x16x32_bf16(af[m], bg[n], acc[m][n], 0, 0, 0);
    __syncthreads();
  }
#pragma unroll
  for (int m = 0; m < 4; ++m)
#pragma unroll
    for (int n = 0; n < 4; ++n)
#pragma unroll
      for (int j = 0; j < 4; ++j) {
        int r = m0 + wr * 64 + m * 16 + lhi * 4 + j;
        int c = n0 + wc * 64 + n * 16 + l15;
        S_b[(long)r * SEQ + c] = acc[m][n][j];
      }
  if (bm != bn) {
#pragma unroll
    for (int m = 0; m < 4; ++m)
#pragma unroll
      for (int n = 0; n < 4; ++n) {
        int r0 = m0 + wr * 64 + m * 16 + lhi * 4;
        int c = n0 + wc * 64 + n * 16 + l15;
        *(f32x4*)&S_b[(long)c * SEQ + r0] = acc[m][n];
      }
  }
}

// ---------------- K3: masked softmax, wave per row ----------------
__global__ __launch_bounds__(256) void k_softmax(
    const float* __restrict__ S, const int* __restrict__ mask,
    unsigned short* __restrict__ P) {
  int w = threadIdx.x >> 6, lane = threadIdx.x & 63;
  long row = (long)blockIdx.x * 4 + w;
  int b = (int)(row >> 11);
  const float* Sp = S + row * SEQ;
  const int* mp = mask + b * SEQ;
  unsigned short* Pp = P + row * SEQ;

  float sv[32];
  float mx = -__builtin_inff();
#pragma unroll
  for (int ci = 0; ci < 8; ++ci) {
    int col = ci * 256 + lane * 4;
    float4 v = *(const float4*)(Sp + col);
    int4 mk = *(const int4*)(mp + col);
    sv[ci * 4 + 0] = mk.x ? v.x : -__builtin_inff();
    sv[ci * 4 + 1] = mk.y ? v.y : -__builtin_inff();
    sv[ci * 4 + 2] = mk.z ? v.z : -__builtin_inff();
    sv[ci * 4 + 3] = mk.w ? v.w : -__builtin_inff();
    mx = fmaxf(mx, fmaxf(fmaxf(sv[ci * 4 + 0], sv[ci * 4 + 1]),
                         fmaxf(sv[ci * 4 + 2], sv[ci * 4 + 3])));
  }
#pragma unroll
  for (int off = 32; off; off >>= 1) mx = fmaxf(mx, __shfl_xor(mx, off));
  float pv[32];
  float sum = 0.0f;
#pragma unroll
  for (int i = 0; i < 32; ++i) {
    pv[i] = expf(sv[i] - mx);
    sum += pv[i];
  }
#pragma unroll
  for (int off = 32; off; off >>= 1) sum += __shfl_xor(sum, off);
  float inv = 1.0f / sum;
#pragma unroll
  for (int ci = 0; ci < 8; ++ci) {
    int col = ci * 256 + lane * 4;
    *(ushort4*)(Pp + col) = make_ushort4(
        f2bf(pv[ci * 4 + 0] * inv), f2bf(pv[ci * 4 + 1] * inv),
        f2bf(pv[ci * 4 + 2] * inv), f2bf(pv[ci * 4 + 3] * inv));
  }
}

// ---------------- K4: context GEMM (NT) + fused epilogue ----------------
// grid (8, 16, 8); batch-per-XCD swizzle; double-buffered LDS prefetch.
__global__ __launch_bounds__(256) void k_context(
    const unsigned short* __restrict__ P, const unsigned short* __restrict__ xT,
    const float* __restrict__ x, float* __restrict__ out) {
  __shared__ unsigned short As[2][128 * BK];
  __shared__ unsigned short Bs[2][128 * BK];
  int p = blockIdx.x + 8 * blockIdx.y + 128 * blockIdx.z;  // 0..1023
  int b = p & 7;            // one batch per XCD
  int q = p >> 3;           // 0..127
  int n0 = (q & 7) * 128;   // d cols; ncol-siblings consecutive -> same XCD,
  int m0 = (q >> 3) * 128;  // co-resident, share the A-panel via L2
  const unsigned short* A_b = P + (long)b * SEQ * SEQ;
  const unsigned short* B_b = xT + (long)b * DIM * SEQ;

  int tid = threadIdx.x;
  int w = tid >> 6, lane = tid & 63;
  int wr = w >> 1, wc = w & 1;
  int l15 = lane & 15, lhi = lane >> 4;

  // per-thread staging constants
  int cbase0 = w * 64;            // chunks 0..255 half (i=0)
  int cbase1 = 256 + w * 64;      // i=1
  int c0 = cbase0 + lane, c1 = cbase1 + lane;
  int row0 = c0 >> 2, row1 = c1 >> 2;
  int kco0 = ((c0 & 3) ^ ((row0 >> 1) & 3)) * 8;
  int kco1 = ((c1 & 3) ^ ((row1 >> 1) & 3)) * 8;
  const unsigned short* Arow0 = A_b + (long)(m0 + row0) * SEQ + kco0;
  const unsigned short* Arow1 = A_b + (long)(m0 + row1) * SEQ + kco1;
  const unsigned short* Brow0 = B_b + (long)(n0 + row0) * SEQ + kco0;
  const unsigned short* Brow1 = B_b + (long)(n0 + row1) * SEQ + kco1;

  f32x4 acc[4][4];
#pragma unroll
  for (int m = 0; m < 4; ++m)
#pragma unroll
    for (int n = 0; n < 4; ++n)
#pragma unroll
      for (int j = 0; j < 4; ++j) acc[m][n][j] = 0.0f;

#define NT_CTX (SEQ / BK)
  // prologue: stage tile 0 into buffer 0
  load16(Arow0, &As[0][cbase0 * 8]);
  load16(Arow1, &As[0][cbase1 * 8]);
  load16(Brow0, &Bs[0][cbase0 * 8]);
  load16(Brow1, &Bs[0][cbase1 * 8]);
  __syncthreads();

  int cur = 0;
  for (int kt = 0; kt < NT_CTX; ++kt) {
    if (kt + 1 < NT_CTX) {
      int kk = (kt + 1) * BK;
      load16(Arow0 + kk, &As[cur ^ 1][cbase0 * 8]);
      load16(Arow1 + kk, &As[cur ^ 1][cbase1 * 8]);
      load16(Brow0 + kk, &Bs[cur ^ 1][cbase0 * 8]);
      load16(Brow1 + kk, &Bs[cur ^ 1][cbase1 * 8]);
    }
    bf16x8 af[4], bg[4];
#pragma unroll
    for (int m = 0; m < 4; ++m) {
      int R = wr * 64 + m * 16 + l15;
      af[m] = *(const bf16x8*)&As[cur][R * BK + ((lhi ^ ((R >> 1) & 3)) * 8)];
    }
#pragma unroll
    for (int n = 0; n < 4; ++n) {
      int R = wc * 64 + n * 16 + l15;
      bg[n] = *(const bf16x8*)&Bs[cur][R * BK + ((lhi ^ ((R >> 1) & 3)) * 8)];
    }
#pragma unroll
    for (int m = 0; m < 4; ++m)
#pragma unroll
      for (int n = 0; n < 4; ++n)
        acc[m][n] = __builtin_amdgcn_mfma_f32_16x16x32_bf16(af[m], bg[n], acc[m][n], 0, 0, 0);
    __syncthreads();  // drains this iter's prefetch (vmcnt0) + protects buf reuse
    cur ^= 1;
  }

  const float* x_b = x + (long)b * SEQ * DIM;
  float* out_b = out + (long)b * SEQ * (5 * DIM);
#pragma unroll
  for (int m = 0; m < 4; ++m)
#pragma unroll
    for (int n = 0; n < 4; ++n)
#pragma unroll
      for (int j = 0; j < 4; ++j) {
        int qi = m0 + wr * 64 + m * 16 + lhi * 4 + j;
        int d = n0 + wc * 64 + n * 16 + l15;
        float c = acc[m][n][j];
        float xv = x_b[(long)qi * DIM + d];
        long base = (long)qi * (5 * DIM) + d;
        out_b[base] = xv;
        out_b[base + DIM] = c;
        out_b[base + 2 * DIM] = xv + c;
        out_b[base + 3 * DIM] = xv - c;
        out_b[base + 4 * DIM] = xv * c;
      }
}

extern "C" void kernel_launch(void* const* d_in, const int* in_sizes, int n_in,
                              void* d_out, int out_size, void* d_ws, size_t ws_size,
                              hipStream_t stream) {
  const float* x = (const float*)d_in[0];
  const int* mask = (const int*)d_in[1];
  float* out = (float*)d_out;
  char* ws = (char*)d_ws;

  const size_t HB = (size_t)NBATCH * SEQ * DIM * 2;
  unsigned short* xh = (unsigned short*)ws;
  unsigned short* xl = (unsigned short*)(ws + HB);
  unsigned short* xT = (unsigned short*)(ws + 2 * HB);
  unsigned short* P = (unsigned short*)(ws + 3 * HB);
  const size_t PB = (size_t)NBATCH * SEQ * SEQ * 2;
  const size_t SB = (size_t)NBATCH * SEQ * SEQ * 4;
  float* S;
  if (ws_size >= 3 * HB + PB + SB) {
    S = (float*)(ws + 3 * HB + PB);
  } else {
    S = (float*)d_out;  // S dead before K4 writes out
  }

  k_prep<<<dim3(SEQ / 32, DIM / 32, NBATCH), 256, 0, stream>>>(x, xh, xl, xT);
  k_scores<<<dim3(136, 1, NBATCH), 256, 0, stream>>>(xh, xl, S);
  k_softmax<<<NBATCH * SEQ / 4, 256, 0, stream>>>(S, mask, P);
  k_context<<<dim3(DIM / 128, SEQ / 128, NBATCH), 256, 0, stream>>>(P, xT, x, out);
}

// Round 4
// 452.886 us; speedup vs baseline: 1.3768x; 1.1241x over previous
//
#include <hip/hip_runtime.h>
#include <hip/hip_bf16.h>

// Biattention: x:[8,2048,1024] f32, mask:[8,2048] i32
// out = concat([x, c, x+c, x-c, x*c], -1) where c = softmax(mask(x x^T)) x
//
// Pipeline:
//  K1 prep:    x -> x_hi(bf16), x_lo(bf16), x_hiT(bf16 transposed)
//  K2 scores:  S = x x^T split-bf16 MFMA GEMM, symmetric tri-blocks, T1 swizzle,
//              2-deep counted-vmcnt pipeline (T4) with raw s_barrier
//  K3 softmax: P = softmax_masked(S) bf16 (wave per row)
//  K4 context: C = P @ x_hi (NT), fused 5-chunk epilogue, T1 + T4 pipeline
//
// T2 swizzle (verified R2: SQ_LDS_BANK_CONFLICT=0): pre-swizzled global source
// chunk (kc4 ^= (row>>1)&3) + same XOR on fragment read.
// T4 (this round): raw s_barrier + s_waitcnt vmcnt(4) keeps 4 loads in flight
// across barriers; __syncthreads' implicit vmcnt(0) was the R3 stall.

typedef __attribute__((ext_vector_type(8))) __bf16 bf16x8;
typedef __attribute__((ext_vector_type(4))) float f32x4;

#define SEQ 2048
#define DIM 1024
#define NBATCH 8
#define BK 32

__device__ __forceinline__ unsigned short f2bf(float f) {
  union { __hip_bfloat16 h; unsigned short u; } cv;
  cv.h = __float2bfloat16(f);
  return cv.u;
}
__device__ __forceinline__ float bf2f(unsigned short u) {
  union { __hip_bfloat16 h; unsigned short u; } cv;
  cv.u = u;
  return __bfloat162float(cv.h);
}

__device__ __forceinline__ void load16(const void* g, void* l) {
  __builtin_amdgcn_global_load_lds(
      (const __attribute__((address_space(1))) unsigned int*)g,
      (__attribute__((address_space(3))) unsigned int*)l, 16, 0, 0);
}

// ---------------- K1: convert + transpose ----------------
__global__ __launch_bounds__(256) void k_prep(
    const float* __restrict__ x, unsigned short* __restrict__ xh,
    unsigned short* __restrict__ xl, unsigned short* __restrict__ xT) {
  __shared__ unsigned short tile[32][33];
  int b = blockIdx.z;
  int s0 = blockIdx.x * 32;
  int d0 = blockIdx.y * 32;
  int t = threadIdx.x;
  int r = t >> 3;
  int c4 = (t & 7) * 4;

  long src = (long)(b * SEQ + s0 + r) * DIM + d0 + c4;
  float4 v = *(const float4*)(x + src);
  float vv[4] = {v.x, v.y, v.z, v.w};
  unsigned short hu[4], lu[4];
#pragma unroll
  for (int j = 0; j < 4; ++j) {
    hu[j] = f2bf(vv[j]);
    float hf = bf2f(hu[j]);
    lu[j] = f2bf(vv[j] - hf);
    tile[r][c4 + j] = hu[j];
  }
  *(ushort4*)(xh + src) = make_ushort4(hu[0], hu[1], hu[2], hu[3]);
  *(ushort4*)(xl + src) = make_ushort4(lu[0], lu[1], lu[2], lu[3]);
  __syncthreads();
  unsigned short tv[4];
#pragma unroll
  for (int j = 0; j < 4; ++j) tv[j] = tile[c4 + j][r];
  long dst = (long)(b * DIM + d0 + r) * SEQ + s0 + c4;
  *(ushort4*)(xT + dst) = make_ushort4(tv[0], tv[1], tv[2], tv[3]);
}

// ---------------- K2: scores GEMM (NT, split-bf16, symmetric, T4) ----------------
#define NT_SC 96
__global__ __launch_bounds__(256) void k_scores(
    const unsigned short* __restrict__ xh, const unsigned short* __restrict__ xl,
    float* __restrict__ S) {
  __shared__ unsigned short As[2][128 * BK];
  __shared__ unsigned short Bs[2][128 * BK];
  int p = blockIdx.x + 136 * blockIdx.z;   // 0..1087
  int b = p & 7;                            // one batch per XCD
  int t = p >> 3;                           // tri-index 0..135
  int bm = 0, rem = 16;
  while (t >= rem) { t -= rem; ++bm; --rem; }
  int bn = bm + t;
  int m0 = bm * 128;
  int n0 = bn * 128;
  const unsigned short* xh_b = xh + (long)b * SEQ * DIM;
  const unsigned short* xl_b = xl + (long)b * SEQ * DIM;
  float* S_b = S + (long)b * SEQ * SEQ;

  int tid = threadIdx.x;
  int w = tid >> 6, lane = tid & 63;
  int wr = w >> 1, wc = w & 1;
  int l15 = lane & 15, lhi = lane >> 4;

  // staging constants (2 chunks per thread per operand)
  int cbase0 = w * 64, cbase1 = 256 + w * 64;
  int c0 = cbase0 + lane, c1 = cbase1 + lane;
  int row0 = c0 >> 2, row1 = c1 >> 2;
  long aoff0 = (long)(m0 + row0) * DIM + ((c0 & 3) ^ ((row0 >> 1) & 3)) * 8;
  long aoff1 = (long)(m0 + row1) * DIM + ((c1 & 3) ^ ((row1 >> 1) & 3)) * 8;
  long boff0 = (long)(n0 + row0) * DIM + ((c0 & 3) ^ ((row0 >> 1) & 3)) * 8;
  long boff1 = (long)(n0 + row1) * DIM + ((c1 & 3) ^ ((row1 >> 1) & 3)) * 8;

#define STAGE_SC(KT, BUF)                                                   \
  {                                                                         \
    int k0_ = (KT) * BK;                                                    \
    int pp_ = k0_ >> 10;                                                    \
    int kk_ = k0_ & 1023;                                                   \
    const unsigned short* As_ = (pp_ == 2) ? xl_b : xh_b;                   \
    const unsigned short* Bs_ = (pp_ == 1) ? xl_b : xh_b;                   \
    load16(As_ + aoff0 + kk_, &As[BUF][cbase0 * 8]);                        \
    load16(As_ + aoff1 + kk_, &As[BUF][cbase1 * 8]);                        \
    load16(Bs_ + boff0 + kk_, &Bs[BUF][cbase0 * 8]);                        \
    load16(Bs_ + boff1 + kk_, &Bs[BUF][cbase1 * 8]);                        \
  }

#define COMPUTE_TILE(ARR_A, ARR_B, BUF)                                     \
  {                                                                         \
    bf16x8 af[4], bg[4];                                                    \
    _Pragma("unroll") for (int m = 0; m < 4; ++m) {                         \
      int R = wr * 64 + m * 16 + l15;                                       \
      af[m] = *(const bf16x8*)&ARR_A[BUF][R * BK + ((lhi ^ ((R >> 1) & 3)) * 8)]; \
    }                                                                       \
    _Pragma("unroll") for (int n = 0; n < 4; ++n) {                         \
      int R = wc * 64 + n * 16 + l15;                                       \
      bg[n] = *(const bf16x8*)&ARR_B[BUF][R * BK + ((lhi ^ ((R >> 1) & 3)) * 8)]; \
    }                                                                       \
    _Pragma("unroll") for (int m = 0; m < 4; ++m)                           \
      _Pragma("unroll") for (int n = 0; n < 4; ++n)                         \
        acc[m][n] = __builtin_amdgcn_mfma_f32_16x16x32_bf16(af[m], bg[n], acc[m][n], 0, 0, 0); \
  }

  f32x4 acc[4][4];
#pragma unroll
  for (int m = 0; m < 4; ++m)
#pragma unroll
    for (int n = 0; n < 4; ++n)
#pragma unroll
      for (int j = 0; j < 4; ++j) acc[m][n][j] = 0.0f;

  // 2-deep pipeline prologue: 8 loads in flight
  STAGE_SC(0, 0);
  STAGE_SC(1, 1);
  for (int kt = 0; kt < NT_SC - 1; ++kt) {
    asm volatile("s_waitcnt vmcnt(4)" ::: "memory");  // stage(kt) landed
    __builtin_amdgcn_s_barrier();
    __builtin_amdgcn_sched_barrier(0);
    COMPUTE_TILE(As, Bs, kt & 1);
    __builtin_amdgcn_sched_barrier(0);
    __builtin_amdgcn_s_barrier();                     // all waves done reading
    if (kt + 2 < NT_SC) STAGE_SC(kt + 2, kt & 1);
  }
  asm volatile("s_waitcnt vmcnt(0)" ::: "memory");
  __builtin_amdgcn_s_barrier();
  COMPUTE_TILE(As, Bs, (NT_SC - 1) & 1);

#pragma unroll
  for (int m = 0; m < 4; ++m)
#pragma unroll
    for (int n = 0; n < 4; ++n)
#pragma unroll
      for (int j = 0; j < 4; ++j) {
        int r = m0 + wr * 64 + m * 16 + lhi * 4 + j;
        int c = n0 + wc * 64 + n * 16 + l15;
        S_b[(long)r * SEQ + c] = acc[m][n][j];
      }
  if (bm != bn) {
#pragma unroll
    for (int m = 0; m < 4; ++m)
#pragma unroll
      for (int n = 0; n < 4; ++n) {
        int r0 = m0 + wr * 64 + m * 16 + lhi * 4;
        int c = n0 + wc * 64 + n * 16 + l15;
        *(f32x4*)&S_b[(long)c * SEQ + r0] = acc[m][n];
      }
  }
}

// ---------------- K3: masked softmax, wave per row ----------------
__global__ __launch_bounds__(256) void k_softmax(
    const float* __restrict__ S, const int* __restrict__ mask,
    unsigned short* __restrict__ P) {
  int w = threadIdx.x >> 6, lane = threadIdx.x & 63;
  long row = (long)blockIdx.x * 4 + w;
  int b = (int)(row >> 11);
  const float* Sp = S + row * SEQ;
  const int* mp = mask + b * SEQ;
  unsigned short* Pp = P + row * SEQ;

  float sv[32];
  float mx = -__builtin_inff();
#pragma unroll
  for (int ci = 0; ci < 8; ++ci) {
    int col = ci * 256 + lane * 4;
    float4 v = *(const float4*)(Sp + col);
    int4 mk = *(const int4*)(mp + col);
    sv[ci * 4 + 0] = mk.x ? v.x : -__builtin_inff();
    sv[ci * 4 + 1] = mk.y ? v.y : -__builtin_inff();
    sv[ci * 4 + 2] = mk.z ? v.z : -__builtin_inff();
    sv[ci * 4 + 3] = mk.w ? v.w : -__builtin_inff();
    mx = fmaxf(mx, fmaxf(fmaxf(sv[ci * 4 + 0], sv[ci * 4 + 1]),
                         fmaxf(sv[ci * 4 + 2], sv[ci * 4 + 3])));
  }
#pragma unroll
  for (int off = 32; off; off >>= 1) mx = fmaxf(mx, __shfl_xor(mx, off));
  float pv[32];
  float sum = 0.0f;
#pragma unroll
  for (int i = 0; i < 32; ++i) {
    pv[i] = expf(sv[i] - mx);
    sum += pv[i];
  }
#pragma unroll
  for (int off = 32; off; off >>= 1) sum += __shfl_xor(sum, off);
  float inv = 1.0f / sum;
#pragma unroll
  for (int ci = 0; ci < 8; ++ci) {
    int col = ci * 256 + lane * 4;
    *(ushort4*)(Pp + col) = make_ushort4(
        f2bf(pv[ci * 4 + 0] * inv), f2bf(pv[ci * 4 + 1] * inv),
        f2bf(pv[ci * 4 + 2] * inv), f2bf(pv[ci * 4 + 3] * inv));
  }
}

// ---------------- K4: context GEMM (NT) + fused epilogue, T4 ----------------
#define NT_CTX 64
__global__ __launch_bounds__(256) void k_context(
    const unsigned short* __restrict__ P, const unsigned short* __restrict__ xT,
    const float* __restrict__ x, float* __restrict__ out) {
  __shared__ unsigned short As[2][128 * BK];
  __shared__ unsigned short Bs[2][128 * BK];
  int p = blockIdx.x + 8 * blockIdx.y + 128 * blockIdx.z;  // 0..1023
  int b = p & 7;            // one batch per XCD
  int q = p >> 3;
  int n0 = (q & 7) * 128;   // ncol-siblings consecutive -> co-resident on XCD
  int m0 = (q >> 3) * 128;
  const unsigned short* A_b = P + (long)b * SEQ * SEQ;
  const unsigned short* B_b = xT + (long)b * DIM * SEQ;

  int tid = threadIdx.x;
  int w = tid >> 6, lane = tid & 63;
  int wr = w >> 1, wc = w & 1;
  int l15 = lane & 15, lhi = lane >> 4;

  int cbase0 = w * 64, cbase1 = 256 + w * 64;
  int c0 = cbase0 + lane, c1 = cbase1 + lane;
  int row0 = c0 >> 2, row1 = c1 >> 2;
  const unsigned short* Arow0 = A_b + (long)(m0 + row0) * SEQ + ((c0 & 3) ^ ((row0 >> 1) & 3)) * 8;
  const unsigned short* Arow1 = A_b + (long)(m0 + row1) * SEQ + ((c1 & 3) ^ ((row1 >> 1) & 3)) * 8;
  const unsigned short* Brow0 = B_b + (long)(n0 + row0) * SEQ + ((c0 & 3) ^ ((row0 >> 1) & 3)) * 8;
  const unsigned short* Brow1 = B_b + (long)(n0 + row1) * SEQ + ((c1 & 3) ^ ((row1 >> 1) & 3)) * 8;

#define STAGE_CTX(KT, BUF)                                \
  {                                                       \
    int kk_ = (KT) * BK;                                  \
    load16(Arow0 + kk_, &As[BUF][cbase0 * 8]);            \
    load16(Arow1 + kk_, &As[BUF][cbase1 * 8]);            \
    load16(Brow0 + kk_, &Bs[BUF][cbase0 * 8]);            \
    load16(Brow1 + kk_, &Bs[BUF][cbase1 * 8]);            \
  }

  f32x4 acc[4][4];
#pragma unroll
  for (int m = 0; m < 4; ++m)
#pragma unroll
    for (int n = 0; n < 4; ++n)
#pragma unroll
      for (int j = 0; j < 4; ++j) acc[m][n][j] = 0.0f;

  STAGE_CTX(0, 0);
  STAGE_CTX(1, 1);
  for (int kt = 0; kt < NT_CTX - 1; ++kt) {
    asm volatile("s_waitcnt vmcnt(4)" ::: "memory");
    __builtin_amdgcn_s_barrier();
    __builtin_amdgcn_sched_barrier(0);
    COMPUTE_TILE(As, Bs, kt & 1);
    __builtin_amdgcn_sched_barrier(0);
    __builtin_amdgcn_s_barrier();
    if (kt + 2 < NT_CTX) STAGE_CTX(kt + 2, kt & 1);
  }
  asm volatile("s_waitcnt vmcnt(0)" ::: "memory");
  __builtin_amdgcn_s_barrier();
  COMPUTE_TILE(As, Bs, (NT_CTX - 1) & 1);

  const float* x_b = x + (long)b * SEQ * DIM;
  float* out_b = out + (long)b * SEQ * (5 * DIM);
#pragma unroll
  for (int m = 0; m < 4; ++m)
#pragma unroll
    for (int n = 0; n < 4; ++n)
#pragma unroll
      for (int j = 0; j < 4; ++j) {
        int qi = m0 + wr * 64 + m * 16 + lhi * 4 + j;
        int d = n0 + wc * 64 + n * 16 + l15;
        float c = acc[m][n][j];
        float xv = x_b[(long)qi * DIM + d];
        long base = (long)qi * (5 * DIM) + d;
        out_b[base] = xv;
        out_b[base + DIM] = c;
        out_b[base + 2 * DIM] = xv + c;
        out_b[base + 3 * DIM] = xv - c;
        out_b[base + 4 * DIM] = xv * c;
      }
}

extern "C" void kernel_launch(void* const* d_in, const int* in_sizes, int n_in,
                              void* d_out, int out_size, void* d_ws, size_t ws_size,
                              hipStream_t stream) {
  const float* x = (const float*)d_in[0];
  const int* mask = (const int*)d_in[1];
  float* out = (float*)d_out;
  char* ws = (char*)d_ws;

  const size_t HB = (size_t)NBATCH * SEQ * DIM * 2;
  unsigned short* xh = (unsigned short*)ws;
  unsigned short* xl = (unsigned short*)(ws + HB);
  unsigned short* xT = (unsigned short*)(ws + 2 * HB);
  unsigned short* P = (unsigned short*)(ws + 3 * HB);
  const size_t PB = (size_t)NBATCH * SEQ * SEQ * 2;
  const size_t SB = (size_t)NBATCH * SEQ * SEQ * 4;
  float* S;
  if (ws_size >= 3 * HB + PB + SB) {
    S = (float*)(ws + 3 * HB + PB);
  } else {
    S = (float*)d_out;  // S dead before K4 writes out
  }

  k_prep<<<dim3(SEQ / 32, DIM / 32, NBATCH), 256, 0, stream>>>(x, xh, xl, xT);
  k_scores<<<dim3(136, 1, NBATCH), 256, 0, stream>>>(xh, xl, S);
  k_softmax<<<NBATCH * SEQ / 4, 256, 0, stream>>>(S, mask, P);
  k_context<<<dim3(DIM / 128, SEQ / 128, NBATCH), 256, 0, stream>>>(P, xT, x, out);
}

// Round 5
// 443.137 us; speedup vs baseline: 1.4070x; 1.0220x over previous
//
#include <hip/hip_runtime.h>
#include <hip/hip_bf16.h>

// Biattention: x:[8,2048,1024] f32, mask:[8,2048] i32
// out = concat([x, c, x+c, x-c, x*c], -1) where c = softmax(mask(x x^T)) x
//
// Pipeline:
//  K1 prep:    x -> x_hi(bf16), x_lo(bf16), x_hiT(bf16 transposed)
//  K2 scores:  S = x x^T split-bf16 MFMA GEMM, symmetric tri-blocks, T1 swizzle,
//              DEPTH-3 counted-vmcnt pipeline (T4) with raw s_barrier
//  K3 softmax: P = softmax_masked(S) bf16 (wave per row)
//  K4 context: C = P @ x_hi (NT), fused 5-chunk epilogue, T1 + depth-3 T4
//
// T2 swizzle (verified R2: SQ_LDS_BANK_CONFLICT=0): pre-swizzled global source
// chunk (kc4 ^= (row>>1)&3) + same XOR on fragment read.
// R4->R5: pipeline depth 2->3. k_context streams P (67MB, first-touch HBM
// misses ~900cyc); 2-deep gave only ~1 iter slack. 3 buffers / vmcnt(8)
// gives ~2 iters (~1800+ cyc) of slack.

typedef __attribute__((ext_vector_type(8))) __bf16 bf16x8;
typedef __attribute__((ext_vector_type(4))) float f32x4;

#define SEQ 2048
#define DIM 1024
#define NBATCH 8
#define BK 32

__device__ __forceinline__ unsigned short f2bf(float f) {
  union { __hip_bfloat16 h; unsigned short u; } cv;
  cv.h = __float2bfloat16(f);
  return cv.u;
}
__device__ __forceinline__ float bf2f(unsigned short u) {
  union { __hip_bfloat16 h; unsigned short u; } cv;
  cv.u = u;
  return __bfloat162float(cv.h);
}

__device__ __forceinline__ void load16(const void* g, void* l) {
  __builtin_amdgcn_global_load_lds(
      (const __attribute__((address_space(1))) unsigned int*)g,
      (__attribute__((address_space(3))) unsigned int*)l, 16, 0, 0);
}

// ---------------- K1: convert + transpose ----------------
__global__ __launch_bounds__(256) void k_prep(
    const float* __restrict__ x, unsigned short* __restrict__ xh,
    unsigned short* __restrict__ xl, unsigned short* __restrict__ xT) {
  __shared__ unsigned short tile[32][33];
  int b = blockIdx.z;
  int s0 = blockIdx.x * 32;
  int d0 = blockIdx.y * 32;
  int t = threadIdx.x;
  int r = t >> 3;
  int c4 = (t & 7) * 4;

  long src = (long)(b * SEQ + s0 + r) * DIM + d0 + c4;
  float4 v = *(const float4*)(x + src);
  float vv[4] = {v.x, v.y, v.z, v.w};
  unsigned short hu[4], lu[4];
#pragma unroll
  for (int j = 0; j < 4; ++j) {
    hu[j] = f2bf(vv[j]);
    float hf = bf2f(hu[j]);
    lu[j] = f2bf(vv[j] - hf);
    tile[r][c4 + j] = hu[j];
  }
  *(ushort4*)(xh + src) = make_ushort4(hu[0], hu[1], hu[2], hu[3]);
  *(ushort4*)(xl + src) = make_ushort4(lu[0], lu[1], lu[2], lu[3]);
  __syncthreads();
  unsigned short tv[4];
#pragma unroll
  for (int j = 0; j < 4; ++j) tv[j] = tile[c4 + j][r];
  long dst = (long)(b * DIM + d0 + r) * SEQ + s0 + c4;
  *(ushort4*)(xT + dst) = make_ushort4(tv[0], tv[1], tv[2], tv[3]);
}

// shared compute macro (declared once, used by both GEMMs)
#define COMPUTE_TILE(ARR_A, ARR_B, BUF)                                     \
  {                                                                         \
    bf16x8 af[4], bg[4];                                                    \
    _Pragma("unroll") for (int m = 0; m < 4; ++m) {                         \
      int R = wr * 64 + m * 16 + l15;                                       \
      af[m] = *(const bf16x8*)&ARR_A[BUF][R * BK + ((lhi ^ ((R >> 1) & 3)) * 8)]; \
    }                                                                       \
    _Pragma("unroll") for (int n = 0; n < 4; ++n) {                         \
      int R = wc * 64 + n * 16 + l15;                                       \
      bg[n] = *(const bf16x8*)&ARR_B[BUF][R * BK + ((lhi ^ ((R >> 1) & 3)) * 8)]; \
    }                                                                       \
    _Pragma("unroll") for (int m = 0; m < 4; ++m)                           \
      _Pragma("unroll") for (int n = 0; n < 4; ++n)                         \
        acc[m][n] = __builtin_amdgcn_mfma_f32_16x16x32_bf16(af[m], bg[n], acc[m][n], 0, 0, 0); \
  }

// ---------------- K2: scores GEMM (NT, split-bf16, symmetric, T4 d3) ----------------
#define NT_SC 96
__global__ __launch_bounds__(256) void k_scores(
    const unsigned short* __restrict__ xh, const unsigned short* __restrict__ xl,
    float* __restrict__ S) {
  __shared__ unsigned short As[3][128 * BK];
  __shared__ unsigned short Bs[3][128 * BK];
  int p = blockIdx.x + 136 * blockIdx.z;   // 0..1087
  int b = p & 7;                            // one batch per XCD
  int t = p >> 3;                           // tri-index 0..135
  int bm = 0, rem = 16;
  while (t >= rem) { t -= rem; ++bm; --rem; }
  int bn = bm + t;
  int m0 = bm * 128;
  int n0 = bn * 128;
  const unsigned short* xh_b = xh + (long)b * SEQ * DIM;
  const unsigned short* xl_b = xl + (long)b * SEQ * DIM;
  float* S_b = S + (long)b * SEQ * SEQ;

  int tid = threadIdx.x;
  int w = tid >> 6, lane = tid & 63;
  int wr = w >> 1, wc = w & 1;
  int l15 = lane & 15, lhi = lane >> 4;

  int cbase0 = w * 64, cbase1 = 256 + w * 64;
  int c0 = cbase0 + lane, c1 = cbase1 + lane;
  int row0 = c0 >> 2, row1 = c1 >> 2;
  long aoff0 = (long)(m0 + row0) * DIM + ((c0 & 3) ^ ((row0 >> 1) & 3)) * 8;
  long aoff1 = (long)(m0 + row1) * DIM + ((c1 & 3) ^ ((row1 >> 1) & 3)) * 8;
  long boff0 = (long)(n0 + row0) * DIM + ((c0 & 3) ^ ((row0 >> 1) & 3)) * 8;
  long boff1 = (long)(n0 + row1) * DIM + ((c1 & 3) ^ ((row1 >> 1) & 3)) * 8;

#define STAGE_SC(KT, BUF)                                                   \
  {                                                                         \
    int k0_ = (KT) * BK;                                                    \
    int pp_ = k0_ >> 10;                                                    \
    int kk_ = k0_ & 1023;                                                   \
    const unsigned short* As_ = (pp_ == 2) ? xl_b : xh_b;                   \
    const unsigned short* Bs_ = (pp_ == 1) ? xl_b : xh_b;                   \
    load16(As_ + aoff0 + kk_, &As[BUF][cbase0 * 8]);                        \
    load16(As_ + aoff1 + kk_, &As[BUF][cbase1 * 8]);                        \
    load16(Bs_ + boff0 + kk_, &Bs[BUF][cbase0 * 8]);                        \
    load16(Bs_ + boff1 + kk_, &Bs[BUF][cbase1 * 8]);                        \
  }

  f32x4 acc[4][4];
#pragma unroll
  for (int m = 0; m < 4; ++m)
#pragma unroll
    for (int n = 0; n < 4; ++n)
#pragma unroll
      for (int j = 0; j < 4; ++j) acc[m][n][j] = 0.0f;

  // depth-3 prologue: 12 loads in flight
  STAGE_SC(0, 0);
  STAGE_SC(1, 1);
  STAGE_SC(2, 2);
  int cur = 0;
  for (int kt = 0; kt < NT_SC - 2; ++kt) {
    asm volatile("s_waitcnt vmcnt(8)" ::: "memory");  // stage(kt) landed
    __builtin_amdgcn_s_barrier();
    __builtin_amdgcn_sched_barrier(0);
    COMPUTE_TILE(As, Bs, cur);
    __builtin_amdgcn_sched_barrier(0);
    __builtin_amdgcn_s_barrier();                     // all waves done reading buf
    if (kt + 3 < NT_SC) STAGE_SC(kt + 3, cur);
    cur = (cur == 2) ? 0 : cur + 1;
  }
  asm volatile("s_waitcnt vmcnt(4)" ::: "memory");
  __builtin_amdgcn_s_barrier();
  COMPUTE_TILE(As, Bs, (NT_SC - 2) % 3);
  asm volatile("s_waitcnt vmcnt(0)" ::: "memory");
  __builtin_amdgcn_s_barrier();
  COMPUTE_TILE(As, Bs, (NT_SC - 1) % 3);

#pragma unroll
  for (int m = 0; m < 4; ++m)
#pragma unroll
    for (int n = 0; n < 4; ++n)
#pragma unroll
      for (int j = 0; j < 4; ++j) {
        int r = m0 + wr * 64 + m * 16 + lhi * 4 + j;
        int c = n0 + wc * 64 + n * 16 + l15;
        S_b[(long)r * SEQ + c] = acc[m][n][j];
      }
  if (bm != bn) {
#pragma unroll
    for (int m = 0; m < 4; ++m)
#pragma unroll
      for (int n = 0; n < 4; ++n) {
        int r0 = m0 + wr * 64 + m * 16 + lhi * 4;
        int c = n0 + wc * 64 + n * 16 + l15;
        *(f32x4*)&S_b[(long)c * SEQ + r0] = acc[m][n];
      }
  }
}

// ---------------- K3: masked softmax, wave per row ----------------
__global__ __launch_bounds__(256) void k_softmax(
    const float* __restrict__ S, const int* __restrict__ mask,
    unsigned short* __restrict__ P) {
  int w = threadIdx.x >> 6, lane = threadIdx.x & 63;
  long row = (long)blockIdx.x * 4 + w;
  int b = (int)(row >> 11);
  const float* Sp = S + row * SEQ;
  const int* mp = mask + b * SEQ;
  unsigned short* Pp = P + row * SEQ;

  float sv[32];
  float mx = -__builtin_inff();
#pragma unroll
  for (int ci = 0; ci < 8; ++ci) {
    int col = ci * 256 + lane * 4;
    float4 v = *(const float4*)(Sp + col);
    int4 mk = *(const int4*)(mp + col);
    sv[ci * 4 + 0] = mk.x ? v.x : -__builtin_inff();
    sv[ci * 4 + 1] = mk.y ? v.y : -__builtin_inff();
    sv[ci * 4 + 2] = mk.z ? v.z : -__builtin_inff();
    sv[ci * 4 + 3] = mk.w ? v.w : -__builtin_inff();
    mx = fmaxf(mx, fmaxf(fmaxf(sv[ci * 4 + 0], sv[ci * 4 + 1]),
                         fmaxf(sv[ci * 4 + 2], sv[ci * 4 + 3])));
  }
#pragma unroll
  for (int off = 32; off; off >>= 1) mx = fmaxf(mx, __shfl_xor(mx, off));
  float pv[32];
  float sum = 0.0f;
#pragma unroll
  for (int i = 0; i < 32; ++i) {
    pv[i] = expf(sv[i] - mx);
    sum += pv[i];
  }
#pragma unroll
  for (int off = 32; off; off >>= 1) sum += __shfl_xor(sum, off);
  float inv = 1.0f / sum;
#pragma unroll
  for (int ci = 0; ci < 8; ++ci) {
    int col = ci * 256 + lane * 4;
    *(ushort4*)(Pp + col) = make_ushort4(
        f2bf(pv[ci * 4 + 0] * inv), f2bf(pv[ci * 4 + 1] * inv),
        f2bf(pv[ci * 4 + 2] * inv), f2bf(pv[ci * 4 + 3] * inv));
  }
}

// ---------------- K4: context GEMM (NT) + fused epilogue, T4 d3 ----------------
#define NT_CTX 64
__global__ __launch_bounds__(256) void k_context(
    const unsigned short* __restrict__ P, const unsigned short* __restrict__ xT,
    const float* __restrict__ x, float* __restrict__ out) {
  __shared__ unsigned short As[3][128 * BK];
  __shared__ unsigned short Bs[3][128 * BK];
  int p = blockIdx.x + 8 * blockIdx.y + 128 * blockIdx.z;  // 0..1023
  int b = p & 7;            // one batch per XCD
  int q = p >> 3;
  int n0 = (q & 7) * 128;   // ncol-siblings consecutive -> co-resident on XCD
  int m0 = (q >> 3) * 128;
  const unsigned short* A_b = P + (long)b * SEQ * SEQ;
  const unsigned short* B_b = xT + (long)b * DIM * SEQ;

  int tid = threadIdx.x;
  int w = tid >> 6, lane = tid & 63;
  int wr = w >> 1, wc = w & 1;
  int l15 = lane & 15, lhi = lane >> 4;

  int cbase0 = w * 64, cbase1 = 256 + w * 64;
  int c0 = cbase0 + lane, c1 = cbase1 + lane;
  int row0 = c0 >> 2, row1 = c1 >> 2;
  const unsigned short* Arow0 = A_b + (long)(m0 + row0) * SEQ + ((c0 & 3) ^ ((row0 >> 1) & 3)) * 8;
  const unsigned short* Arow1 = A_b + (long)(m0 + row1) * SEQ + ((c1 & 3) ^ ((row1 >> 1) & 3)) * 8;
  const unsigned short* Brow0 = B_b + (long)(n0 + row0) * SEQ + ((c0 & 3) ^ ((row0 >> 1) & 3)) * 8;
  const unsigned short* Brow1 = B_b + (long)(n0 + row1) * SEQ + ((c1 & 3) ^ ((row1 >> 1) & 3)) * 8;

#define STAGE_CTX(KT, BUF)                                \
  {                                                       \
    int kk_ = (KT) * BK;                                  \
    load16(Arow0 + kk_, &As[BUF][cbase0 * 8]);            \
    load16(Arow1 + kk_, &As[BUF][cbase1 * 8]);            \
    load16(Brow0 + kk_, &Bs[BUF][cbase0 * 8]);            \
    load16(Brow1 + kk_, &Bs[BUF][cbase1 * 8]);            \
  }

  f32x4 acc[4][4];
#pragma unroll
  for (int m = 0; m < 4; ++m)
#pragma unroll
    for (int n = 0; n < 4; ++n)
#pragma unroll
      for (int j = 0; j < 4; ++j) acc[m][n][j] = 0.0f;

  STAGE_CTX(0, 0);
  STAGE_CTX(1, 1);
  STAGE_CTX(2, 2);
  int cur = 0;
  for (int kt = 0; kt < NT_CTX - 2; ++kt) {
    asm volatile("s_waitcnt vmcnt(8)" ::: "memory");
    __builtin_amdgcn_s_barrier();
    __builtin_amdgcn_sched_barrier(0);
    COMPUTE_TILE(As, Bs, cur);
    __builtin_amdgcn_sched_barrier(0);
    __builtin_amdgcn_s_barrier();
    if (kt + 3 < NT_CTX) STAGE_CTX(kt + 3, cur);
    cur = (cur == 2) ? 0 : cur + 1;
  }
  asm volatile("s_waitcnt vmcnt(4)" ::: "memory");
  __builtin_amdgcn_s_barrier();
  COMPUTE_TILE(As, Bs, (NT_CTX - 2) % 3);
  asm volatile("s_waitcnt vmcnt(0)" ::: "memory");
  __builtin_amdgcn_s_barrier();
  COMPUTE_TILE(As, Bs, (NT_CTX - 1) % 3);

  const float* x_b = x + (long)b * SEQ * DIM;
  float* out_b = out + (long)b * SEQ * (5 * DIM);
#pragma unroll
  for (int m = 0; m < 4; ++m)
#pragma unroll
    for (int n = 0; n < 4; ++n)
#pragma unroll
      for (int j = 0; j < 4; ++j) {
        int qi = m0 + wr * 64 + m * 16 + lhi * 4 + j;
        int d = n0 + wc * 64 + n * 16 + l15;
        float c = acc[m][n][j];
        float xv = x_b[(long)qi * DIM + d];
        long base = (long)qi * (5 * DIM) + d;
        out_b[base] = xv;
        out_b[base + DIM] = c;
        out_b[base + 2 * DIM] = xv + c;
        out_b[base + 3 * DIM] = xv - c;
        out_b[base + 4 * DIM] = xv * c;
      }
}

extern "C" void kernel_launch(void* const* d_in, const int* in_sizes, int n_in,
                              void* d_out, int out_size, void* d_ws, size_t ws_size,
                              hipStream_t stream) {
  const float* x = (const float*)d_in[0];
  const int* mask = (const int*)d_in[1];
  float* out = (float*)d_out;
  char* ws = (char*)d_ws;

  const size_t HB = (size_t)NBATCH * SEQ * DIM * 2;
  unsigned short* xh = (unsigned short*)ws;
  unsigned short* xl = (unsigned short*)(ws + HB);
  unsigned short* xT = (unsigned short*)(ws + 2 * HB);
  unsigned short* P = (unsigned short*)(ws + 3 * HB);
  const size_t PB = (size_t)NBATCH * SEQ * SEQ * 2;
  const size_t SB = (size_t)NBATCH * SEQ * SEQ * 4;
  float* S;
  if (ws_size >= 3 * HB + PB + SB) {
    S = (float*)(ws + 3 * HB + PB);
  } else {
    S = (float*)d_out;  // S dead before K4 writes out
  }

  k_prep<<<dim3(SEQ / 32, DIM / 32, NBATCH), 256, 0, stream>>>(x, xh, xl, xT);
  k_scores<<<dim3(136, 1, NBATCH), 256, 0, stream>>>(xh, xl, S);
  k_softmax<<<NBATCH * SEQ / 4, 256, 0, stream>>>(S, mask, P);
  k_context<<<dim3(DIM / 128, SEQ / 128, NBATCH), 256, 0, stream>>>(P, xT, x, out);
}